// Round 3
// baseline (593.031 us; speedup 1.0000x reference)
//
#include <hip/hip_runtime.h>

#define NBLOCKS 4096
#define WPB 4
#define BLOCK 256

__device__ __forceinline__ float sel4(int b, float x0, float x1, float x2, float x3) {
    float r = x3;
    r = (b == 2) ? x2 : r;
    r = (b == 1) ? x1 : r;
    r = (b == 0) ? x0 : r;
    return r;
}

__device__ __forceinline__ float fast_tanh(float x) {
    float e = __expf(2.f * x);
    return 1.f - 2.f / (e + 1.f);
}

__device__ __forceinline__ float wred(float v) {
    v += __shfl_xor(v, 32, 64);
    v += __shfl_xor(v, 16, 64);
    v += __shfl_xor(v, 8, 64);
    v += __shfl_xor(v, 4, 64);
    v += __shfl_xor(v, 2, 64);
    v += __shfl_xor(v, 1, 64);
    return v;
}

__global__ __launch_bounds__(BLOCK, 6) void einstein_kernel(
    const float* __restrict__ coords,
    const float* __restrict__ gW1, const float* __restrict__ gb1,
    const float* __restrict__ gW2, const float* __restrict__ gb2,
    const float* __restrict__ gW3, const float* __restrict__ gb3,
    const float* __restrict__ gW4, const float* __restrict__ gb4,
    float* __restrict__ out, int B)
{
    __shared__ __align__(16) float st[WPB][64 * 20];   // [hidden][15 state slots + pad]
    __shared__ __align__(16) float gammaB[WPB][64];
    __shared__ __align__(16) float dgammaB[WPB][256];
    __shared__ __align__(16) float ricciB[WPB][16];
    __shared__ __align__(16) float fjkB[WPB][16];

    const int wv = threadIdx.x >> 6;
    const int lane = threadIdx.x & 63;
    float* stw = st[wv];
    float* gmB = gammaB[wv];
    float* dgmB = dgammaB[wv];
    float* rcB = ricciB[wv];
    float* fkB = fjkB[wv];

    // per-lane (hidden unit = lane) constants, loaded once (L1/L2 hit)
    const float w1c0 = gW1[0 * 64 + lane];
    const float w1c1 = gW1[1 * 64 + lane];
    const float w1c2 = gW1[2 * 64 + lane];
    const float w1c3 = gW1[3 * 64 + lane];
    const float b1c = gb1[lane], b2c = gb2[lane], b3c = gb3[lane];
    const float w4c = gW4[lane];
    const float b4v = gb4[0];

    const int wid = blockIdx.x * WPB + wv;
    const int nw = NBLOCKS * WPB;

    for (int p = wid; p < B; p += nw) {
        const float4 c4 = reinterpret_cast<const float4*>(coords)[p];
        const float cr = c4.y, cth = c4.z;

        // ---------- layer 1 (4 -> 64); input tangents are e_j, second-order zero
        float u = b1c + c4.x * w1c0 + cr * w1c1 + cth * w1c2 + c4.w * w1c3;
        float y = fast_tanh(u);
        float D = 1.f - y * y;
        float m2 = -2.f * y * D;
        float z0 = y;
        float z1 = D * w1c0, z2 = D * w1c1, z3 = D * w1c2, z4 = D * w1c3;
        float z5 = m2 * w1c0 * w1c0, z6 = m2 * w1c0 * w1c1, z7 = m2 * w1c0 * w1c2, z8 = m2 * w1c0 * w1c3;
        float z9 = m2 * w1c1 * w1c1, z10 = m2 * w1c1 * w1c2, z11 = m2 * w1c1 * w1c3;
        float z12 = m2 * w1c2 * w1c2, z13 = m2 * w1c2 * w1c3, z14 = m2 * w1c3 * w1c3;

        {
            float4* row = reinterpret_cast<float4*>(stw + lane * 20);
            row[0] = make_float4(z0, z1, z2, z3);
            row[1] = make_float4(z4, z5, z6, z7);
            row[2] = make_float4(z8, z9, z10, z11);
            row[3] = make_float4(z12, z13, z14, 0.f);
        }
        asm volatile("s_waitcnt lgkmcnt(0)" ::: "memory");

        // ---------- layers 2 and 3 (64 -> 64), 15 jet vectors each
        #pragma unroll 1
        for (int LL = 0; LL < 2; ++LL) {
            const float* __restrict__ W = (LL ? gW3 : gW2) + lane;
            float a0 = LL ? b3c : b2c;
            float a1 = 0, a2 = 0, a3 = 0, a4 = 0, a5 = 0, a6 = 0, a7 = 0;
            float a8 = 0, a9 = 0, a10 = 0, a11 = 0, a12 = 0, a13 = 0, a14 = 0;
            #pragma unroll 8
            for (int i = 0; i < 64; ++i) {
                const float4* row = reinterpret_cast<const float4*>(stw + i * 20);
                float4 v0 = row[0];
                float4 v1 = row[1];
                float4 v2 = row[2];
                float4 v3 = row[3];
                float w = W[i * 64];
                a0 += v0.x * w; a1 += v0.y * w; a2 += v0.z * w; a3 += v0.w * w;
                a4 += v1.x * w; a5 += v1.y * w; a6 += v1.z * w; a7 += v1.w * w;
                a8 += v2.x * w; a9 += v2.y * w; a10 += v2.z * w; a11 += v2.w * w;
                a12 += v3.x * w; a13 += v3.y * w; a14 += v3.z * w;
            }
            y = fast_tanh(a0);
            D = 1.f - y * y;
            m2 = -2.f * y * D;
            z0 = y;
            z1 = D * a1; z2 = D * a2; z3 = D * a3; z4 = D * a4;
            z5 = D * a5 + m2 * a1 * a1;
            z6 = D * a6 + m2 * a1 * a2;
            z7 = D * a7 + m2 * a1 * a3;
            z8 = D * a8 + m2 * a1 * a4;
            z9 = D * a9 + m2 * a2 * a2;
            z10 = D * a10 + m2 * a2 * a3;
            z11 = D * a11 + m2 * a2 * a4;
            z12 = D * a12 + m2 * a3 * a3;
            z13 = D * a13 + m2 * a3 * a4;
            z14 = D * a14 + m2 * a4 * a4;
            if (LL == 0) {
                float4* row = reinterpret_cast<float4*>(stw + lane * 20);
                row[0] = make_float4(z0, z1, z2, z3);
                row[1] = make_float4(z4, z5, z6, z7);
                row[2] = make_float4(z8, z9, z10, z11);
                row[3] = make_float4(z12, z13, z14, 0.f);
                asm volatile("s_waitcnt lgkmcnt(0)" ::: "memory");
            }
        }

        // ---------- final linear layer (64 -> 1): wave reductions
        const float f = wred(w4c * z0) + b4v;
        const float fj0 = wred(w4c * z1);
        const float fj1 = wred(w4c * z2);
        const float fj2 = wred(w4c * z3);
        const float fj3 = wred(w4c * z4);
        const float s00 = wred(w4c * z5);
        const float s01 = wred(w4c * z6);
        const float s02 = wred(w4c * z7);
        const float s03 = wred(w4c * z8);
        const float s11 = wred(w4c * z9);
        const float s12 = wred(w4c * z10);
        const float s13 = wred(w4c * z11);
        const float s22 = wred(w4c * z12);
        const float s23 = wred(w4c * z13);
        const float s33 = wred(w4c * z14);

        // ---------- analytic Einstein tensor
        // metric diag: g = (-1, E=exp(f), r^2, r^2 sin^2 th)
        float S, Cq;
        __sincosf(cth, &S, &Cq);
        const float E = __expf(f);
        const float r2v = cr * cr, S2 = S * S;
        const float GI1 = 1.f / E;
        const float GI2 = 1.f / r2v;
        const float GI3 = GI2 / S2;
        const float d3_r = 2.f * cr * S2;            // d g33 / dr
        const float d3_th = 2.f * r2v * S * Cq;      // d g33 / dth
        const float dd_rr = 2.f * S2;
        const float dd_rth = 4.f * cr * S * Cq;
        const float dd_thth = 2.f * r2v * (Cq * Cq - S2);

        // stage full Hessian of f (4x4) into LDS for runtime-index access
        if (lane < 16) {
            const int jj = lane >> 2, kk = lane & 3;
            const int lo = jj < kk ? jj : kk, hi = jj < kk ? kk : jj;
            const int code = lo * 4 + hi;
            float v = s33;
            v = code == 0 ? s00 : v;  v = code == 1 ? s01 : v;  v = code == 2 ? s02 : v;
            v = code == 3 ? s03 : v;  v = code == 5 ? s11 : v;  v = code == 6 ? s12 : v;
            v = code == 7 ? s13 : v;  v = code == 10 ? s22 : v; v = code == 11 ? s23 : v;
            fkB[lane] = v;
        }
        asm volatile("s_waitcnt lgkmcnt(0)" ::: "memory");

        auto fjsel = [&](int b) { return sel4(b, fj0, fj1, fj2, fj3); };
        // d g_aa / d x^b
        auto dgd = [&](int a, int b) {
            float v1 = E * fjsel(b);
            float v2 = (b == 1) ? (2.f * cr) : 0.f;
            float v3 = (b == 1) ? d3_r : ((b == 2) ? d3_th : 0.f);
            return (a == 1) ? v1 : ((a == 2) ? v2 : ((a == 3) ? v3 : 0.f));
        };
        // d2 g_aa / d x^b d x^l
        auto d2f = [&](int a, int b, int l) {
            float v1 = E * (fjsel(b) * fjsel(l) + fkB[b * 4 + l]);
            float v2 = (b == 1 && l == 1) ? 2.f : 0.f;
            float v3 = (b == 1 && l == 1) ? dd_rr
                       : (((b == 1 && l == 2) || (b == 2 && l == 1)) ? dd_rth
                       : ((b == 2 && l == 2) ? dd_thth : 0.f));
            return (a == 1) ? v1 : ((a == 2) ? v2 : ((a == 3) ? v3 : 0.f));
        };

        // each lane computes Gamma^i_{kj} and its 4 derivatives;  lane = i*16+k*4+j
        const int li = (lane >> 4) & 3, lk = (lane >> 2) & 3, lj = lane & 3;
        const float GIi = sel4(li, -1.f, GI1, GI2, GI3);
        float P = (lk == li ? dgd(li, lj) : 0.f)
                + (lj == li ? dgd(li, lk) : 0.f)
                - (lj == lk ? dgd(lj, li) : 0.f);
        gmB[lane] = 0.5f * GIi * P;
        const float GIi2 = GIi * GIi;
        float dgm0, dgm1, dgm2, dgm3;
        {
            float Q0 = (lk == li ? d2f(li, lj, 0) : 0.f) + (lj == li ? d2f(li, lk, 0) : 0.f) - (lj == lk ? d2f(lj, li, 0) : 0.f);
            float Q1 = (lk == li ? d2f(li, lj, 1) : 0.f) + (lj == li ? d2f(li, lk, 1) : 0.f) - (lj == lk ? d2f(lj, li, 1) : 0.f);
            float Q2 = (lk == li ? d2f(li, lj, 2) : 0.f) + (lj == li ? d2f(li, lk, 2) : 0.f) - (lj == lk ? d2f(lj, li, 2) : 0.f);
            float Q3 = (lk == li ? d2f(li, lj, 3) : 0.f) + (lj == li ? d2f(li, lk, 3) : 0.f) - (lj == lk ? d2f(lj, li, 3) : 0.f);
            dgm0 = 0.5f * (GIi * Q0 - dgd(li, 0) * GIi2 * P);
            dgm1 = 0.5f * (GIi * Q1 - dgd(li, 1) * GIi2 * P);
            dgm2 = 0.5f * (GIi * Q2 - dgd(li, 2) * GIi2 * P);
            dgm3 = 0.5f * (GIi * Q3 - dgd(li, 3) * GIi2 * P);
        }
        reinterpret_cast<float4*>(dgmB)[lane] = make_float4(dgm0, dgm1, dgm2, dgm3);
        asm volatile("s_waitcnt lgkmcnt(0)" ::: "memory");

        // ricci[j][k] = sum_m G^m_jk T_m - sum_{m,i} G^m_ji G^i_mk + sum_i d_i G^i_jk - d_k T_j
        if (lane < 16) {
            const int j = lane >> 2, k = lane & 3;
            float T0 = 0, T1 = 0, T2 = 0, T3 = 0;
            #pragma unroll
            for (int i = 0; i < 4; ++i) {
                T0 += gmB[i * 16 + 0 + i];
                T1 += gmB[i * 16 + 4 + i];
                T2 += gmB[i * 16 + 8 + i];
                T3 += gmB[i * 16 + 12 + i];
            }
            float t1 = gmB[0 + j * 4 + k] * T0 + gmB[16 + j * 4 + k] * T1
                     + gmB[32 + j * 4 + k] * T2 + gmB[48 + j * 4 + k] * T3;
            float t2 = 0.f;
            #pragma unroll
            for (int m = 0; m < 4; ++m) {
                #pragma unroll
                for (int i = 0; i < 4; ++i)
                    t2 += gmB[m * 16 + j * 4 + i] * gmB[i * 16 + m * 4 + k];
            }
            float t3 = 0.f, t4 = 0.f;
            #pragma unroll
            for (int i = 0; i < 4; ++i) {
                t3 += dgmB[(i * 16 + j * 4 + k) * 4 + i];
                t4 += dgmB[(i * 16 + j * 4 + i) * 4 + k];
            }
            rcB[lane] = t1 - t2 + t3 - t4;
        }
        asm volatile("s_waitcnt lgkmcnt(0)" ::: "memory");

        if (lane < 16) {
            const int j = lane >> 2, k = lane & 3;
            const float R = -rcB[0] + GI1 * rcB[5] + GI2 * rcB[10] + GI3 * rcB[15];
            const float GIj = sel4(j, -1.f, GI1, GI2, GI3);
            const float GIk = sel4(k, -1.f, GI1, GI2, GI3);
            const float o = GIj * GIk * rcB[lane] - ((j == k) ? 0.5f * R * GIj : 0.f);
            out[p * 16 + lane] = o;
        }
    }
}

extern "C" void kernel_launch(void* const* d_in, const int* in_sizes, int n_in,
                              void* d_out, int out_size, void* d_ws, size_t ws_size,
                              hipStream_t stream) {
    const float* coords = (const float*)d_in[0];
    const float* W1 = (const float*)d_in[1];
    const float* b1 = (const float*)d_in[2];
    const float* W2 = (const float*)d_in[3];
    const float* b2 = (const float*)d_in[4];
    const float* W3 = (const float*)d_in[5];
    const float* b3 = (const float*)d_in[6];
    const float* W4 = (const float*)d_in[7];
    const float* b4 = (const float*)d_in[8];
    const int B = in_sizes[0] / 4;

    hipLaunchKernelGGL(einstein_kernel, dim3(NBLOCKS), dim3(BLOCK), 0, stream,
                       coords, W1, b1, W2, b2, W3, b3, W4, b4,
                       (float*)d_out, B);
}

// Round 4
// 187.344 us; speedup vs baseline: 3.1655x; 3.1655x over previous
//
#include <hip/hip_runtime.h>

#define NBLOCKS 4096
#define WPB 4
#define BLOCK 256

typedef __attribute__((ext_vector_type(8))) short sh8;
typedef __attribute__((ext_vector_type(4))) float f32x4;

__device__ __forceinline__ float sel4(int b, float x0, float x1, float x2, float x3) {
    float r = x3;
    r = (b == 2) ? x2 : r;
    r = (b == 1) ? x1 : r;
    r = (b == 0) ? x0 : r;
    return r;
}

__device__ __forceinline__ float fast_tanh(float x) {
    float e = __expf(2.f * x);
    return 1.f - 2.f / (e + 1.f);
}

__device__ __forceinline__ float wred(float v) {
    v += __shfl_xor(v, 32, 64);
    v += __shfl_xor(v, 16, 64);
    v += __shfl_xor(v, 8, 64);
    v += __shfl_xor(v, 4, 64);
    v += __shfl_xor(v, 2, 64);
    v += __shfl_xor(v, 1, 64);
    return v;
}

// swizzled bf16 index into a [rows][64] LDS array (row stride = 32 dwords).
// XOR of (row&7)<<2 into the column-dword bits keeps b128 row-column reads
// at the 8-slot floor instead of 16-way conflicts.
__device__ __forceinline__ int zidx(int m, int u) {
    return (((m << 5) + (((u >> 1) ^ ((m & 7) << 2)))) << 1) + (u & 1);
}

// load an 8x-bf16 MFMA fragment: row = matrix row, lanes' k-slice = kt*32 + g*8
__device__ __forceinline__ sh8 ldfrag(const unsigned short* base, int row, int g, int kt) {
    const int dw = (row << 5) + ((((kt << 4) + (g << 2))) ^ ((row & 7) << 2));
    return *(const sh8*)(base + (dw << 1));
}

// split f32 into truncated-bf16 hi and bf16(x-hi) lo; hi+lo ~ x to 2^-16 rel
__device__ __forceinline__ void wsplit(float x, unsigned short& h, unsigned short& l) {
    const unsigned ub = __float_as_uint(x);
    const unsigned hb = ub & 0xffff0000u;
    const float lf = x - __uint_as_float(hb);
    h = (unsigned short)(hb >> 16);
    l = (unsigned short)(__float_as_uint(lf) >> 16);
}

__global__ __launch_bounds__(BLOCK, 3) void einstein_kernel(
    const float* __restrict__ coords,
    const float* __restrict__ gW1, const float* __restrict__ gb1,
    const float* __restrict__ gW2, const float* __restrict__ gb2,
    const float* __restrict__ gW3, const float* __restrict__ gb3,
    const float* __restrict__ gW4, const float* __restrict__ gb4,
    float* __restrict__ out, int B)
{
    // weights (Wl after restage) transposed+swizzled: [layer][out 64][in 64] bf16
    __shared__ __align__(16) unsigned short wlds[2][4096];
    // per-wave state (jets x units) bf16 hi/lo, swizzled
    __shared__ __align__(16) unsigned short zhS[WPB][1024];
    __shared__ __align__(16) unsigned short zlS[WPB][1024];
    // per-wave scratch: C scatter/gather [16][68] f32; later aliased by epilogue
    __shared__ __align__(16) float cbS[WPB][1088];

    const int wv = threadIdx.x >> 6;
    const int lane = threadIdx.x & 63;
    const int n15 = lane & 15;
    const int g4 = lane >> 4;
    unsigned short* zh = zhS[wv];
    unsigned short* zl = zlS[wv];
    float* cb = cbS[wv];
    float* gmB = cb;          // 64
    float* dgmB = cb + 64;    // 256
    float* rcB = cb + 320;    // 16
    float* fkB = cb + 336;    // 16

    // ---- stage Wh (truncated-bf16) into LDS, pull fragments to registers ----
    for (int e = threadIdx.x; e < 4096; e += BLOCK) {
        const int o = e & 63, i = e >> 6;
        unsigned short h2, l2, h3, l3;
        wsplit(gW2[i * 64 + o], h2, l2);
        wsplit(gW3[i * 64 + o], h3, l3);
        const int ix = zidx(o, i);
        wlds[0][ix] = h2;
        wlds[1][ix] = h3;
    }
    __syncthreads();
    sh8 Whf[2][4][2];
    #pragma unroll
    for (int L = 0; L < 2; ++L)
        #pragma unroll
        for (int nt = 0; nt < 4; ++nt)
            #pragma unroll
            for (int kt = 0; kt < 2; ++kt)
                Whf[L][nt][kt] = ldfrag(wlds[L], nt * 16 + n15, g4, kt);
    __syncthreads();
    // ---- restage with Wl (low bf16 residual) ----
    for (int e = threadIdx.x; e < 4096; e += BLOCK) {
        const int o = e & 63, i = e >> 6;
        unsigned short h2, l2, h3, l3;
        wsplit(gW2[i * 64 + o], h2, l2);
        wsplit(gW3[i * 64 + o], h3, l3);
        const int ix = zidx(o, i);
        wlds[0][ix] = l2;
        wlds[1][ix] = l3;
    }
    __syncthreads();

    // zero pad row 15 of the state (A-row 15 must be clean zeros)
    zh[zidx(15, lane)] = 0;
    zl[zidx(15, lane)] = 0;
    asm volatile("s_waitcnt lgkmcnt(0)" ::: "memory");

    // per-lane layer-1 constants (lane = hidden unit)
    const float w1c0 = gW1[0 * 64 + lane];
    const float w1c1 = gW1[1 * 64 + lane];
    const float w1c2 = gW1[2 * 64 + lane];
    const float w1c3 = gW1[3 * 64 + lane];
    const float b1c = gb1[lane], b2c = gb2[lane], b3c = gb3[lane];
    const float w4c = gW4[lane];
    const float b4v = gb4[0];

    const int wid = blockIdx.x * WPB + wv;
    const int nw = NBLOCKS * WPB;

    for (int p = wid; p < B; p += nw) {
        const float4 c4 = reinterpret_cast<const float4*>(coords)[p];
        const float cr = c4.y, cth = c4.z;

        float z[15];
        // ---------- layer 1 (4 -> 64), closed-form jet, lane = unit
        {
            const float u = b1c + c4.x * w1c0 + cr * w1c1 + cth * w1c2 + c4.w * w1c3;
            const float y = fast_tanh(u);
            const float D = 1.f - y * y;
            const float m2 = -2.f * y * D;
            z[0] = y;
            z[1] = D * w1c0; z[2] = D * w1c1; z[3] = D * w1c2; z[4] = D * w1c3;
            z[5] = m2 * w1c0 * w1c0; z[6] = m2 * w1c0 * w1c1; z[7] = m2 * w1c0 * w1c2; z[8] = m2 * w1c0 * w1c3;
            z[9] = m2 * w1c1 * w1c1; z[10] = m2 * w1c1 * w1c2; z[11] = m2 * w1c1 * w1c3;
            z[12] = m2 * w1c2 * w1c2; z[13] = m2 * w1c2 * w1c3; z[14] = m2 * w1c3 * w1c3;
        }
        #pragma unroll
        for (int m = 0; m < 15; ++m) {
            unsigned short h, l;
            wsplit(z[m], h, l);
            const int ix = zidx(m, lane);
            zh[ix] = h;
            zl[ix] = l;
        }
        asm volatile("s_waitcnt lgkmcnt(0)" ::: "memory");

        // ---------- layers 2,3: jet-GEMM on MFMA with hi/lo split
        #pragma unroll
        for (int LL = 0; LL < 2; ++LL) {
            const unsigned short* wl = wlds[LL];
            const sh8 Ah0 = ldfrag(zh, n15, g4, 0);
            const sh8 Ah1 = ldfrag(zh, n15, g4, 1);
            const sh8 Al0 = ldfrag(zl, n15, g4, 0);
            const sh8 Al1 = ldfrag(zl, n15, g4, 1);
            f32x4 acc[4];
            #pragma unroll
            for (int nt = 0; nt < 4; ++nt) {
                f32x4 a0 = {0.f, 0.f, 0.f, 0.f};
                const sh8 Bl0 = ldfrag(wl, nt * 16 + n15, g4, 0);
                const sh8 Bl1 = ldfrag(wl, nt * 16 + n15, g4, 1);
                a0 = __builtin_amdgcn_mfma_f32_16x16x32_bf16(Ah0, Whf[LL][nt][0], a0, 0, 0, 0);
                a0 = __builtin_amdgcn_mfma_f32_16x16x32_bf16(Ah1, Whf[LL][nt][1], a0, 0, 0, 0);
                a0 = __builtin_amdgcn_mfma_f32_16x16x32_bf16(Al0, Whf[LL][nt][0], a0, 0, 0, 0);
                a0 = __builtin_amdgcn_mfma_f32_16x16x32_bf16(Al1, Whf[LL][nt][1], a0, 0, 0, 0);
                a0 = __builtin_amdgcn_mfma_f32_16x16x32_bf16(Ah0, Bl0, a0, 0, 0, 0);
                a0 = __builtin_amdgcn_mfma_f32_16x16x32_bf16(Ah1, Bl1, a0, 0, 0, 0);
                acc[nt] = a0;
            }
            // scatter C (jet m = g4*4+j, unit = nt*16+n15) into padded cbuf
            #pragma unroll
            for (int nt = 0; nt < 4; ++nt)
                #pragma unroll
                for (int j = 0; j < 4; ++j)
                    cb[(g4 * 4 + j) * 68 + nt * 16 + n15] = acc[nt][j];
            asm volatile("s_waitcnt lgkmcnt(0)" ::: "memory");
            // gather: lane = unit, all 15 jets
            float a[15];
            #pragma unroll
            for (int m = 0; m < 15; ++m) a[m] = cb[m * 68 + lane];

            const float a0v = a[0] + (LL ? b3c : b2c);
            const float y = fast_tanh(a0v);
            const float D = 1.f - y * y;
            const float m2 = -2.f * y * D;
            z[0] = y;
            z[1] = D * a[1]; z[2] = D * a[2]; z[3] = D * a[3]; z[4] = D * a[4];
            z[5] = D * a[5] + m2 * a[1] * a[1];
            z[6] = D * a[6] + m2 * a[1] * a[2];
            z[7] = D * a[7] + m2 * a[1] * a[3];
            z[8] = D * a[8] + m2 * a[1] * a[4];
            z[9] = D * a[9] + m2 * a[2] * a[2];
            z[10] = D * a[10] + m2 * a[2] * a[3];
            z[11] = D * a[11] + m2 * a[2] * a[4];
            z[12] = D * a[12] + m2 * a[3] * a[3];
            z[13] = D * a[13] + m2 * a[3] * a[4];
            z[14] = D * a[14] + m2 * a[4] * a[4];

            if (LL == 0) {
                #pragma unroll
                for (int m = 0; m < 15; ++m) {
                    unsigned short h, l;
                    wsplit(z[m], h, l);
                    const int ix = zidx(m, lane);
                    zh[ix] = h;
                    zl[ix] = l;
                }
                asm volatile("s_waitcnt lgkmcnt(0)" ::: "memory");
            }
        }

        // ---------- final linear layer (64 -> 1): wave reductions
        const float f = wred(w4c * z[0]) + b4v;
        const float fj0 = wred(w4c * z[1]);
        const float fj1 = wred(w4c * z[2]);
        const float fj2 = wred(w4c * z[3]);
        const float fj3 = wred(w4c * z[4]);
        const float s00 = wred(w4c * z[5]);
        const float s01 = wred(w4c * z[6]);
        const float s02 = wred(w4c * z[7]);
        const float s03 = wred(w4c * z[8]);
        const float s11 = wred(w4c * z[9]);
        const float s12 = wred(w4c * z[10]);
        const float s13 = wred(w4c * z[11]);
        const float s22 = wred(w4c * z[12]);
        const float s23 = wred(w4c * z[13]);
        const float s33 = wred(w4c * z[14]);

        // ---------- analytic Einstein tensor
        float S, Cq;
        __sincosf(cth, &S, &Cq);
        const float E = __expf(f);
        const float r2v = cr * cr, S2 = S * S;
        const float GI1 = 1.f / E;
        const float GI2 = 1.f / r2v;
        const float GI3 = GI2 / S2;
        const float d3_r = 2.f * cr * S2;
        const float d3_th = 2.f * r2v * S * Cq;
        const float dd_rr = 2.f * S2;
        const float dd_rth = 4.f * cr * S * Cq;
        const float dd_thth = 2.f * r2v * (Cq * Cq - S2);

        if (lane < 16) {
            const int jj = lane >> 2, kk = lane & 3;
            const int lo = jj < kk ? jj : kk, hi = jj < kk ? kk : jj;
            const int code = lo * 4 + hi;
            float v = s33;
            v = code == 0 ? s00 : v;  v = code == 1 ? s01 : v;  v = code == 2 ? s02 : v;
            v = code == 3 ? s03 : v;  v = code == 5 ? s11 : v;  v = code == 6 ? s12 : v;
            v = code == 7 ? s13 : v;  v = code == 10 ? s22 : v; v = code == 11 ? s23 : v;
            fkB[lane] = v;
        }
        asm volatile("s_waitcnt lgkmcnt(0)" ::: "memory");

        auto fjsel = [&](int b) { return sel4(b, fj0, fj1, fj2, fj3); };
        auto dgd = [&](int a, int b) {
            float v1 = E * fjsel(b);
            float v2 = (b == 1) ? (2.f * cr) : 0.f;
            float v3 = (b == 1) ? d3_r : ((b == 2) ? d3_th : 0.f);
            return (a == 1) ? v1 : ((a == 2) ? v2 : ((a == 3) ? v3 : 0.f));
        };
        auto d2f = [&](int a, int b, int l) {
            float v1 = E * (fjsel(b) * fjsel(l) + fkB[b * 4 + l]);
            float v2 = (b == 1 && l == 1) ? 2.f : 0.f;
            float v3 = (b == 1 && l == 1) ? dd_rr
                       : (((b == 1 && l == 2) || (b == 2 && l == 1)) ? dd_rth
                       : ((b == 2 && l == 2) ? dd_thth : 0.f));
            return (a == 1) ? v1 : ((a == 2) ? v2 : ((a == 3) ? v3 : 0.f));
        };

        const int li = (lane >> 4) & 3, lk = (lane >> 2) & 3, lj = lane & 3;
        const float GIi = sel4(li, -1.f, GI1, GI2, GI3);
        float P = (lk == li ? dgd(li, lj) : 0.f)
                + (lj == li ? dgd(li, lk) : 0.f)
                - (lj == lk ? dgd(lj, li) : 0.f);
        gmB[lane] = 0.5f * GIi * P;
        const float GIi2 = GIi * GIi;
        float dgm0, dgm1, dgm2, dgm3;
        {
            float Q0 = (lk == li ? d2f(li, lj, 0) : 0.f) + (lj == li ? d2f(li, lk, 0) : 0.f) - (lj == lk ? d2f(lj, li, 0) : 0.f);
            float Q1 = (lk == li ? d2f(li, lj, 1) : 0.f) + (lj == li ? d2f(li, lk, 1) : 0.f) - (lj == lk ? d2f(lj, li, 1) : 0.f);
            float Q2 = (lk == li ? d2f(li, lj, 2) : 0.f) + (lj == li ? d2f(li, lk, 2) : 0.f) - (lj == lk ? d2f(lj, li, 2) : 0.f);
            float Q3 = (lk == li ? d2f(li, lj, 3) : 0.f) + (lj == li ? d2f(li, lk, 3) : 0.f) - (lj == lk ? d2f(lj, li, 3) : 0.f);
            dgm0 = 0.5f * (GIi * Q0 - dgd(li, 0) * GIi2 * P);
            dgm1 = 0.5f * (GIi * Q1 - dgd(li, 1) * GIi2 * P);
            dgm2 = 0.5f * (GIi * Q2 - dgd(li, 2) * GIi2 * P);
            dgm3 = 0.5f * (GIi * Q3 - dgd(li, 3) * GIi2 * P);
        }
        reinterpret_cast<float4*>(dgmB)[lane] = make_float4(dgm0, dgm1, dgm2, dgm3);
        asm volatile("s_waitcnt lgkmcnt(0)" ::: "memory");

        if (lane < 16) {
            const int j = lane >> 2, k = lane & 3;
            float T0 = 0, T1 = 0, T2 = 0, T3 = 0;
            #pragma unroll
            for (int i = 0; i < 4; ++i) {
                T0 += gmB[i * 16 + 0 + i];
                T1 += gmB[i * 16 + 4 + i];
                T2 += gmB[i * 16 + 8 + i];
                T3 += gmB[i * 16 + 12 + i];
            }
            float t1 = gmB[0 + j * 4 + k] * T0 + gmB[16 + j * 4 + k] * T1
                     + gmB[32 + j * 4 + k] * T2 + gmB[48 + j * 4 + k] * T3;
            float t2 = 0.f;
            #pragma unroll
            for (int m = 0; m < 4; ++m) {
                #pragma unroll
                for (int i = 0; i < 4; ++i)
                    t2 += gmB[m * 16 + j * 4 + i] * gmB[i * 16 + m * 4 + k];
            }
            float t3 = 0.f, t4 = 0.f;
            #pragma unroll
            for (int i = 0; i < 4; ++i) {
                t3 += dgmB[(i * 16 + j * 4 + k) * 4 + i];
                t4 += dgmB[(i * 16 + j * 4 + i) * 4 + k];
            }
            rcB[lane] = t1 - t2 + t3 - t4;
        }
        asm volatile("s_waitcnt lgkmcnt(0)" ::: "memory");

        if (lane < 16) {
            const int j = lane >> 2, k = lane & 3;
            const float R = -rcB[0] + GI1 * rcB[5] + GI2 * rcB[10] + GI3 * rcB[15];
            const float GIj = sel4(j, -1.f, GI1, GI2, GI3);
            const float GIk = sel4(k, -1.f, GI1, GI2, GI3);
            const float o = GIj * GIk * rcB[lane] - ((j == k) ? 0.5f * R * GIj : 0.f);
            out[p * 16 + lane] = o;
        }
        asm volatile("s_waitcnt lgkmcnt(0)" ::: "memory");
    }
}

extern "C" void kernel_launch(void* const* d_in, const int* in_sizes, int n_in,
                              void* d_out, int out_size, void* d_ws, size_t ws_size,
                              hipStream_t stream) {
    const float* coords = (const float*)d_in[0];
    const float* W1 = (const float*)d_in[1];
    const float* b1 = (const float*)d_in[2];
    const float* W2 = (const float*)d_in[3];
    const float* b2 = (const float*)d_in[4];
    const float* W3 = (const float*)d_in[5];
    const float* b3 = (const float*)d_in[6];
    const float* W4 = (const float*)d_in[7];
    const float* b4 = (const float*)d_in[8];
    const int B = in_sizes[0] / 4;

    hipLaunchKernelGGL(einstein_kernel, dim3(NBLOCKS), dim3(BLOCK), 0, stream,
                       coords, W1, b1, W2, b2, W3, b3, W4, b4,
                       (float*)d_out, B);
}